// Round 15
// baseline (153.567 us; speedup 1.0000x reference)
//
#include <hip/hip_runtime.h>
#include <math.h>

// Problem shape (fixed by the reference): B=4, S=4, N=2048, D=2048
#define NB 4
#define NS 4
#define NN 2048
#define ND 2048
#define NTHREADS 256     // 4 waves per block, ONE INDEPENDENT bn PER WAVE
#define SQRT_D 45.254833995939045f   // sqrt(2048)

typedef float f32x4 __attribute__((ext_vector_type(4)));

// Compaction-butterfly ship, literal indices only (R3 lesson, R5/R9-proven).
#define SHIP(I, H, M_) {                                      \
    const float keep_ = hi_ ? v[(I)+(H)] : v[(I)];            \
    const float give_ = hi_ ? v[(I)] : v[(I)+(H)];            \
    v[(I)] = keep_ + __shfl_xor(give_, (M_)); }

#define BUTTERFLY()                                                          \
    { const bool hi_ = (lane & 1) != 0;                                      \
      SHIP(0,16,1)  SHIP(1,16,1)  SHIP(2,16,1)  SHIP(3,16,1)                 \
      SHIP(4,16,1)  SHIP(5,16,1)  SHIP(6,16,1)  SHIP(7,16,1)                 \
      SHIP(8,16,1)  SHIP(9,16,1)  SHIP(10,16,1) SHIP(11,16,1)                \
      SHIP(12,16,1) SHIP(13,16,1) SHIP(14,16,1) SHIP(15,16,1) }              \
    { const bool hi_ = (lane & 2) != 0;                                      \
      SHIP(0,8,2) SHIP(1,8,2) SHIP(2,8,2) SHIP(3,8,2)                        \
      SHIP(4,8,2) SHIP(5,8,2) SHIP(6,8,2) SHIP(7,8,2) }                      \
    { const bool hi_ = (lane & 4) != 0;                                      \
      SHIP(0,4,4) SHIP(1,4,4) SHIP(2,4,4) SHIP(3,4,4) }                      \
    { const bool hi_ = (lane & 8) != 0;                                      \
      SHIP(0,2,8) SHIP(1,2,8) }                                              \
    { const bool hi_ = (lane & 16) != 0;                                     \
      SHIP(0,1,16) }

// brev5 as a compile-time-shaped bit expression (valid for 0..31)
#define BREV5(k) ((((k) & 1) << 4) | (((k) & 2) << 2) | ((k) & 4) \
                | (((k) & 8) >> 2) | (((k) & 16) >> 4))

// One wave per (b,n): no barriers, no LDS, fully independent waves.
// Lane covers chunks d = c*256 + lane*4, c = 0..7, of all 4 rows.
__global__ __launch_bounds__(NTHREADS, 4)
void hyperconn_kernel(const float* __restrict__ residuals,
                      const float* __restrict__ gamma,
                      const float* __restrict__ w_alpha,
                      const float* __restrict__ scale_alpha,
                      const float* __restrict__ static_alpha,
                      const float* __restrict__ w_beta,
                      const float* __restrict__ scale_beta,
                      const float* __restrict__ static_beta,
                      float* __restrict__ out)
{
    const int tid  = threadIdx.x;
    const int wave = tid >> 6;
    const int lane = tid & 63;
    const int bn   = blockIdx.x * 4 + wave;   // one bn per wave
    const int b    = bn >> 11;
    const int n    = bn & (NN - 1);
    const int dl   = lane << 2;               // lane's base offset in a chunk

    const size_t row_stride = (size_t)NN * ND;
    const float* xw = residuals + (size_t)(b * NS) * row_stride + (size_t)n * ND;
    float*       ow = out       + (size_t)(b * NS) * row_stride + (size_t)n * ND;

    // Per-lane epilogue constants (lane l<24 owns tanh (s,j)=(l/6,l%6))
    const float sa = scale_alpha[0], sb = scale_beta[0];
    const int l24 = (lane < 24) ? lane : 0;
    const int es = l24 / 6, ej = l24 % 6;
    const float stat = (ej < 5) ? static_alpha[es * 5 + ej] : static_beta[es];
    // After BUTTERFLY, lane l holds value brev5(l&31); value k lives in lane BREV5(k)
    const int src_ssq = BREV5(es * 7);
    const int src_dot = BREV5(es * 7 + 1 + ej);

    // ---- Dots: v[s*7]=ssq(x[s]); v[s*7+1+j]=dot(x[s], w_j*(1+g)); pad to 32 ----
    float v[32];
#pragma unroll
    for (int k = 0; k < 32; ++k) v[k] = 0.f;

#pragma unroll
    for (int c = 0; c < 8; ++c) {
        const int d = c * 256 + dl;
        f32x4 x0 = *(const f32x4*)(xw + d);
        f32x4 x1 = *(const f32x4*)(xw + row_stride + d);
        f32x4 x2 = *(const f32x4*)(xw + 2 * row_stride + d);
        f32x4 x3 = *(const f32x4*)(xw + 3 * row_stride + d);
        f32x4 g4 = *(const f32x4*)(gamma + d);
#pragma unroll
        for (int e = 0; e < 4; ++e) {
            v[0]  = __builtin_fmaf(x0[e], x0[e], v[0]);
            v[7]  = __builtin_fmaf(x1[e], x1[e], v[7]);
            v[14] = __builtin_fmaf(x2[e], x2[e], v[14]);
            v[21] = __builtin_fmaf(x3[e], x3[e], v[21]);
        }
#pragma unroll
        for (int j = 0; j < 6; ++j) {
            const float* wsrc = (j < 5) ? (w_alpha + (size_t)j * ND + d)
                                        : (w_beta + d);
            f32x4 w4 = *(const f32x4*)wsrc;
            f32x4 wg = w4 + w4 * g4;       // w * (1 + gamma)
#pragma unroll
            for (int e = 0; e < 4; ++e) {
                v[1 + j]  = __builtin_fmaf(x0[e], wg[e], v[1 + j]);
                v[8 + j]  = __builtin_fmaf(x1[e], wg[e], v[8 + j]);
                v[15 + j] = __builtin_fmaf(x2[e], wg[e], v[15 + j]);
                v[22 + j] = __builtin_fmaf(x3[e], wg[e], v[22 + j]);
            }
        }
        // x0..x3 die per-chunk; apply re-reads from L2 (32 KB, ~500cy later)
    }

    // ---- Wave-internal reduction: 31 ships + 1 xor32; lane l holds brev5(l&31) ----
    BUTTERFLY()
    const float tot = v[0] + __shfl_xor(v[0], 32);

    // ---- In-wave epilogue: lane l<24 computes one tanh; M via shfl (R4/R6-proven) ----
    const float ssq = __shfl(tot, src_ssq);
    const float dot = __shfl(tot, src_dot);
    const float rs  = SQRT_D / fmaxf(sqrtf(ssq), 1e-12f);
    const float aval = __builtin_fmaf(tanhf(dot * rs), (ej < 5) ? sa : sb, stat);

    float a0[4];
#pragma unroll
    for (int si = 0; si < 4; ++si) a0[si] = __shfl(aval, si * 6);
    float M[4][4];
#pragma unroll
    for (int so = 0; so < 4; ++so) {
        const float bso = __shfl(aval, so * 6 + 5);
#pragma unroll
        for (int si = 0; si < 4; ++si)
            M[so][si] = __builtin_fmaf(bso, a0[si], __shfl(aval, si * 6 + so + 1));
    }

    // ---- Apply: re-read x (L2-hot), out[so] = sum_si M[so][si]*x[si] ----
#pragma unroll
    for (int c = 0; c < 8; ++c) {
        const int d = c * 256 + dl;
        f32x4 y0 = *(const f32x4*)(xw + d);
        f32x4 y1 = *(const f32x4*)(xw + row_stride + d);
        f32x4 y2 = *(const f32x4*)(xw + 2 * row_stride + d);
        f32x4 y3 = *(const f32x4*)(xw + 3 * row_stride + d);
#pragma unroll
        for (int so = 0; so < 4; ++so) {
            f32x4 o;
#pragma unroll
            for (int e = 0; e < 4; ++e)
                o[e] = M[so][0] * y0[e] + M[so][1] * y1[e]
                     + M[so][2] * y2[e] + M[so][3] * y3[e];
            __builtin_nontemporal_store(o, (f32x4*)(ow + (size_t)so * row_stride + d));
        }
    }
}

extern "C" void kernel_launch(void* const* d_in, const int* in_sizes, int n_in,
                              void* d_out, int out_size, void* d_ws, size_t ws_size,
                              hipStream_t stream) {
    const float* residuals    = (const float*)d_in[0];
    const float* gamma        = (const float*)d_in[1];
    const float* w_alpha      = (const float*)d_in[2];
    const float* scale_alpha  = (const float*)d_in[3];
    const float* static_alpha = (const float*)d_in[4];
    const float* w_beta       = (const float*)d_in[5];
    const float* scale_beta   = (const float*)d_in[6];
    const float* static_beta  = (const float*)d_in[7];
    float* out = (float*)d_out;

    const int grid = NB * NN / 4;  // 2048 blocks x 4 waves = 8192 bn
    hyperconn_kernel<<<grid, NTHREADS, 0, stream>>>(
        residuals, gamma, w_alpha, scale_alpha, static_alpha,
        w_beta, scale_beta, static_beta, out);
}